// Round 2
// baseline (1951.879 us; speedup 1.0000x reference)
//
#include <hip/hip_runtime.h>
#include <cstdint>

#define NND 5000
#define NE 160000
#define NF 128
#define NH 256
#define NT 10
#define MT 10
#define NC 8
#define NMAT (NND*MT)      // 50000 per template
#define CG_ITERS 5
#define SINK_IT 30
#define BPT 8              // blocks per template
#define RPB 625            // rows per block (8*625 = 5000)
#define NGENS 168          // sync generations per template (5*32 = 160 used)
#define SPAD 32            // int padding for flag/cnt (128B lines)

// ---------------- graph prep ----------------

__global__ void k_count(const int* __restrict__ dst, int* __restrict__ cnt) {
    for (int e = blockIdx.x*blockDim.x + threadIdx.x; e < NE; e += gridDim.x*blockDim.x)
        atomicAdd(&cnt[dst[e]], 1);
}

__global__ void k_dinv(const int* __restrict__ cnt, float* __restrict__ dinv) {
    for (int v = blockIdx.x*blockDim.x + threadIdx.x; v < NND; v += gridDim.x*blockDim.x)
        dinv[v] = rsqrtf((float)(cnt[v] + 1));   // +1 self loop; always >= 1
}

__global__ void k_exscan(const int* __restrict__ cnt, int* __restrict__ rp, int n) {
    const int T = 1024;
    int tid = threadIdx.x;
    int C = (n + T - 1) / T;
    int begin = tid * C, end = begin + C; if (end > n) end = n; if (begin > n) begin = n;
    int s = 0;
    for (int i = begin; i < end; i++) s += cnt[i];
    __shared__ int part[1024];
    part[tid] = s; __syncthreads();
    for (int off = 1; off < T; off <<= 1) {
        int v = (tid >= off) ? part[tid - off] : 0;
        __syncthreads();
        part[tid] += v;
        __syncthreads();
    }
    int run = part[tid] - s;   // exclusive
    for (int i = begin; i < end; i++) { rp[i] = run; run += cnt[i]; }
    if (tid == T - 1) rp[n] = part[T - 1];
}

__global__ void k_scatter_dst(const int* __restrict__ src, const int* __restrict__ dst,
                              const int* __restrict__ rp, int* __restrict__ cur,
                              int* __restrict__ csrS, float* __restrict__ csrC,
                              const float* __restrict__ dinv) {
    for (int e = blockIdx.x*blockDim.x + threadIdx.x; e < NE; e += gridDim.x*blockDim.x) {
        int s = src[e], d = dst[e];
        int pos = rp[d] + atomicAdd(&cur[d], 1);
        csrS[pos] = s;
        csrC[pos] = dinv[s] * dinv[d];
    }
}

__global__ void k_dedup(const int* __restrict__ src, const int* __restrict__ dst,
                        unsigned* __restrict__ bitmap, int* __restrict__ cntS,
                        unsigned char* __restrict__ keep) {
    for (int e = blockIdx.x*blockDim.x + threadIdx.x; e < NE; e += gridDim.x*blockDim.x) {
        int s = src[e], d = dst[e];
        int key = s * NND + d;
        unsigned bit = 1u << (key & 31);
        unsigned old = atomicOr(&bitmap[key >> 5], bit);
        if (!(old & bit)) { keep[e] = 1; atomicAdd(&cntS[s], 1); }
        else keep[e] = 0;
    }
}

__global__ void k_scatter_src(const int* __restrict__ src, const int* __restrict__ dst,
                              const unsigned char* __restrict__ keep,
                              const int* __restrict__ rp, int* __restrict__ cur,
                              int* __restrict__ csrD) {
    for (int e = blockIdx.x*blockDim.x + threadIdx.x; e < NE; e += gridDim.x*blockDim.x) {
        if (keep[e]) {
            int s = src[e];
            int pos = rp[s] + atomicAdd(&cur[s], 1);
            csrD[pos] = dst[e];
        }
    }
}

// ---------------- GCN ----------------

__global__ __launch_bounds__(256) void k_gemm(const float* __restrict__ A,
                                              const float* __restrict__ B,
                                              float* __restrict__ C, int M, int N, int K) {
    const int BM = 64, BN = 64, BK = 16;
    __shared__ float As[BK][BM + 1];
    __shared__ float Bs[BK][BN];
    int tid = threadIdx.x;
    int row0 = blockIdx.y * BM, col0 = blockIdx.x * BN;
    int tx = tid % 16, ty = tid / 16;
    float acc[4][4] = {};
    for (int k0 = 0; k0 < K; k0 += BK) {
#pragma unroll
        for (int l = 0; l < 4; l++) {
            int idx = tid + l * 256;
            int r = idx / BK, kk = idx % BK;
            int gr = row0 + r;
            As[kk][r] = (gr < M) ? A[(size_t)gr * K + k0 + kk] : 0.f;
        }
#pragma unroll
        for (int l = 0; l < 4; l++) {
            int idx = tid + l * 256;
            int kk = idx / BN, c = idx % BN;
            Bs[kk][c] = B[(size_t)(k0 + kk) * N + col0 + c];
        }
        __syncthreads();
#pragma unroll
        for (int kk = 0; kk < BK; kk++) {
            float a[4], b[4];
#pragma unroll
            for (int i = 0; i < 4; i++) a[i] = As[kk][ty * 4 + i];
#pragma unroll
            for (int j = 0; j < 4; j++) b[j] = Bs[kk][tx * 4 + j];
#pragma unroll
            for (int i = 0; i < 4; i++)
#pragma unroll
                for (int j = 0; j < 4; j++) acc[i][j] += a[i] * b[j];
        }
        __syncthreads();
    }
#pragma unroll
    for (int i = 0; i < 4; i++) {
        int gr = row0 + ty * 4 + i;
        if (gr < M) {
#pragma unroll
            for (int j = 0; j < 4; j++)
                C[(size_t)gr * N + col0 + tx * 4 + j] = acc[i][j];
        }
    }
}

__global__ void k_aggregate(const float* __restrict__ hin, const float* __restrict__ bias,
                            float* __restrict__ hout, const int* __restrict__ rp,
                            const int* __restrict__ csrS, const float* __restrict__ csrC,
                            const float* __restrict__ dinv, int relu) {
    int v = blockIdx.x;
    int f = threadIdx.x;
    int F = blockDim.x;
    float dv = dinv[v];
    float acc = hin[(size_t)v * F + f] * dv * dv;   // structural self-loop
    int e0 = rp[v], e1 = rp[v + 1];
    for (int e = e0; e < e1; e++)
        acc += hin[(size_t)csrS[e] * F + f] * csrC[e];
    acc += bias[f];
    if (relu) acc = fmaxf(acc, 0.f);
    hout[(size_t)v * F + f] = acc;
}

// ---------------- FGW prep ----------------

__global__ void k_prep_nodes(const int* __restrict__ cntS, const float* __restrict__ h,
                             float* __restrict__ c1row, float* __restrict__ sx) {
    for (int i = blockIdx.x*blockDim.x + threadIdx.x; i < NND; i += gridDim.x*blockDim.x) {
        c1row[i] = (float)cntS[i] * (1.f / NND);
        float s = 0.f;
        for (int f = 0; f < NF; f++) { float v = h[(size_t)i * NF + f]; s += v * v; }
        sx[i] = s;
    }
}

__global__ void k_prep_tpl(const float* __restrict__ tpl, const float* __restrict__ tplF,
                           float* __restrict__ c2row, float* __restrict__ sF) {
    int c = threadIdx.x;
    if (c < NT * MT) {
        int t = c / MT, j = c % MT;
        float s = 0.f;
        for (int k = 0; k < MT; k++) { float v = tpl[t * 100 + j * 10 + k]; s += v * v; }
        c2row[c] = s * (1.f / MT);
        float sf = 0.f;
        for (int f = 0; f < NF; f++) { float v = tplF[(size_t)c * NF + f]; sf += v * v; }
        sF[c] = sf;
    }
}

__global__ void k_M(const float* __restrict__ h, const float* __restrict__ tplF,
                    const float* __restrict__ sx, const float* __restrict__ sF,
                    float* __restrict__ Mout) {
    int i = blockIdx.x;
    __shared__ float hrow[NF];
    hrow[threadIdx.x] = h[(size_t)i * NF + threadIdx.x];
    __syncthreads();
    int c = threadIdx.x;
    if (c < NT * MT) {
        const float* Fc = tplF + (size_t)c * NF;
        float dot = 0.f;
        for (int f = 0; f < NF; f++) dot += hrow[f] * Fc[f];
        int t = c / MT, j = c % MT;
        Mout[(size_t)t * NMAT + (size_t)i * MT + j] = sx[i] + sF[c] - 2.f * dot;
    }
}

__global__ void k_Tinit(float* __restrict__ T) {
    for (int idx = blockIdx.x*blockDim.x + threadIdx.x; idx < NT * NMAT; idx += gridDim.x*blockDim.x)
        T[idx] = 1.f / (float)NMAT;
}

// ---------------- fused persistent FGW kernel ----------------

// T accessed as 8-byte relaxed AGENT atomics (coherence point) for cross-XCD
// visibility between T-update and the next CG's gradient gather.
__device__ __forceinline__ void t_load2(const float* p, float& a, float& b) {
    unsigned long long v = __hip_atomic_load((const unsigned long long*)p,
                                             __ATOMIC_RELAXED, __HIP_MEMORY_SCOPE_AGENT);
    a = __uint_as_float((unsigned)v);
    b = __uint_as_float((unsigned)(v >> 32));
}
__device__ __forceinline__ void t_store2(float* p, float a, float b) {
    unsigned long long v = (unsigned long long)__float_as_uint(a) |
                           ((unsigned long long)__float_as_uint(b) << 32);
    __hip_atomic_store((unsigned long long*)p, v, __ATOMIC_RELAXED, __HIP_MEMORY_SCOPE_AGENT);
}

// device-scope barrier across the BPT blocks of one template.
// mode 0: flag only; mode 1: publish scale from maxU; mode 2: publish v = q/colsum.
// call only after a __syncthreads() (so all the block's memory ops are drained).
__device__ __forceinline__ void g_arrive_spin(int t, int gen, int mode,
    int* cnt, int* flag, unsigned* maxU, double* accD, double* payD,
    double* vsh, int tid)
{
    if (tid == 0) {
        __threadfence();
        int old = __hip_atomic_fetch_add(&cnt[t*SPAD], 1,
                                         __ATOMIC_ACQ_REL, __HIP_MEMORY_SCOPE_AGENT);
        if (old == gen*BPT - 1) {          // last arriver of this generation
            size_t s16 = ((size_t)t*NGENS + gen)*16;
            if (mode == 1) {
                unsigned bits = __hip_atomic_load(&maxU[t*NGENS + gen],
                                                  __ATOMIC_RELAXED, __HIP_MEMORY_SCOPE_AGENT);
                payD[s16] = (double)__uint_as_float(bits);
            } else if (mode == 2) {
#pragma unroll
                for (int j = 0; j < 10; j++) {
                    double sv = __hip_atomic_load(&accD[s16 + j],
                                                  __ATOMIC_RELAXED, __HIP_MEMORY_SCOPE_AGENT);
                    payD[s16 + j] = 0.1 / sv;           // v = q / (K^T u), q = 1/MT
                }
            }
            __threadfence();
            __hip_atomic_store(&flag[t*SPAD], gen,
                               __ATOMIC_RELEASE, __HIP_MEMORY_SCOPE_AGENT);
        }
        while (__hip_atomic_load(&flag[t*SPAD],
                                 __ATOMIC_RELAXED, __HIP_MEMORY_SCOPE_AGENT) < gen)
            __builtin_amdgcn_s_sleep(1);
        __threadfence();                    // acquire: invalidate caches before payload/T reads
        if (mode) {
            size_t s16 = ((size_t)t*NGENS + gen)*16;
            int np = (mode == 1) ? 1 : 10;
            for (int j = 0; j < np; j++) vsh[j] = payD[s16 + j];
        }
    }
    __syncthreads();
}

__global__ __launch_bounds__(512, 1) void k_fgw(
    const float* __restrict__ Mm, float* __restrict__ T,
    const float* __restrict__ c1row, const float* __restrict__ c2row,
    const float* __restrict__ tpl, const int* __restrict__ rpS,
    const int* __restrict__ csrD,
    int* cnt, int* flag, unsigned* maxU, double* accD, double* payD,
    double* dd)
{
    int bid = blockIdx.x;
    int t = bid % NT, chunk = bid / NT;
    int tid = threadIdx.x;
    int lane = tid & 63, w = tid >> 6;

    __shared__ double red[10][512];   // 40 KB: column partials / final reduce
    __shared__ double vsh[16];
    __shared__ float tC2[100];
    __shared__ float wmax[8];

    if (tid < 100) tC2[tid] = 2.f * tpl[t*100 + tid];

    const float* Mt = Mm + (size_t)t * NMAT;
    float* Tt = T + (size_t)t * NMAT;

    int i0 = chunk*RPB + tid;
    int i1 = i0 + 512;
    bool has1 = (tid + 512 < RPB);
    if (!has1) i1 = i0;                       // safe dummy

    float c2r[10];
#pragma unroll
    for (int j = 0; j < 10; j++) c2r[j] = c2row[t*10 + j];
    float c1_0 = c1row[i0];
    float c1_1 = has1 ? c1row[i1] : 0.f;
    int e00 = rpS[i0], e01 = rpS[i0+1];
    int e10 = has1 ? rpS[i1] : 0, e11 = has1 ? rpS[i1+1] : 0;
    float m0[10], m1[10];
    {
        const float2* Mr = (const float2*)(Mt + (size_t)i0*10);
#pragma unroll
        for (int h = 0; h < 5; h++) { float2 v = Mr[h]; m0[2*h]=v.x; m0[2*h+1]=v.y; }
        const float2* Mr1 = (const float2*)(Mt + (size_t)i1*10);
#pragma unroll
        for (int h = 0; h < 5; h++) { float2 v = Mr1[h]; m1[2*h]=v.x; m1[2*h+1]=v.y; }
    }

    float K0[10], K1[10];          // holds G during grad phase, then K = exp(G*inv)
    double vv[10];
    double u0 = 1.0, u1 = 0.0;

    __syncthreads();   // tC2 ready

    for (int c = 0; c < CG_ITERS; c++) {
        // ---- gradient rows (held in registers) ----
        float amax = 0.f;
        {
            float L[10];
#pragma unroll
            for (int j = 0; j < 10; j++) L[j] = 0.f;
            for (int e = e00; e < e01; e++) {
                const float* Tk = Tt + (size_t)csrD[e]*10;
#pragma unroll
                for (int h = 0; h < 5; h++) { float a, b; t_load2(Tk + 2*h, a, b); L[2*h]+=a; L[2*h+1]+=b; }
            }
#pragma unroll
            for (int j = 0; j < 10; j++) {
                float s = 0.f;
#pragma unroll
                for (int k = 0; k < 10; k++) s += L[k]*tC2[j*10+k];
                float g = 0.5f*m0[j] + c1_0 + c2r[j] - s;
                K0[j] = g; amax = fmaxf(amax, fabsf(g));
            }
        }
        if (has1) {
            float L[10];
#pragma unroll
            for (int j = 0; j < 10; j++) L[j] = 0.f;
            for (int e = e10; e < e11; e++) {
                const float* Tk = Tt + (size_t)csrD[e]*10;
#pragma unroll
                for (int h = 0; h < 5; h++) { float a, b; t_load2(Tk + 2*h, a, b); L[2*h]+=a; L[2*h+1]+=b; }
            }
#pragma unroll
            for (int j = 0; j < 10; j++) {
                float s = 0.f;
#pragma unroll
                for (int k = 0; k < 10; k++) s += L[k]*tC2[j*10+k];
                float g = 0.5f*m1[j] + c1_1 + c2r[j] - s;
                K1[j] = g; amax = fmaxf(amax, fabsf(g));
            }
        }
        // ---- global absmax -> Sinkhorn scale ----
#pragma unroll
        for (int off = 32; off; off >>= 1) amax = fmaxf(amax, __shfl_down(amax, off));
        if (lane == 0) wmax[w] = amax;
        __syncthreads();
        int gen = c*32 + 1;
        if (tid == 0) {
            float mm = wmax[0];
#pragma unroll
            for (int i = 1; i < 8; i++) mm = fmaxf(mm, wmax[i]);
            atomicMax(&maxU[t*NGENS + gen], __float_as_uint(mm));
        }
        __syncthreads();
        g_arrive_spin(t, gen, 1, cnt, flag, maxU, accD, payD, vsh, tid);
        float scale = (float)vsh[0];
        float inv = -1.f / (0.02f * (scale + 1e-9f));
#pragma unroll
        for (int j = 0; j < 10; j++) K0[j] = __expf(K0[j]*inv);
        if (has1) {
#pragma unroll
            for (int j = 0; j < 10; j++) K1[j] = __expf(K1[j]*inv);
        } else {
#pragma unroll
            for (int j = 0; j < 10; j++) K1[j] = 0.f;
        }
        u0 = 1.0; u1 = has1 ? 1.0 : 0.0;

        // ---- 30 Sinkhorn iterations (one device-scope sync each) ----
        for (int it = 0; it < SINK_IT; it++) {
#pragma unroll
            for (int j = 0; j < 10; j++)
                red[j][tid] = (double)K0[j]*u0 + (double)K1[j]*u1;
            __syncthreads();
            int g2 = c*32 + 2 + it;
            size_t s16 = ((size_t)t*NGENS + g2)*16;
#pragma unroll
            for (int job = 0; job < 2; job++) {
                int j = w + job*8;
                if (j < 10) {
                    double s = 0.0;
#pragma unroll
                    for (int q8 = 0; q8 < 8; q8++) s += red[j][lane + q8*64];
#pragma unroll
                    for (int off = 32; off; off >>= 1) s += __shfl_down(s, off);
                    if (lane == 0) atomicAdd(&accD[s16 + j], s);
                }
            }
            __syncthreads();
            g_arrive_spin(t, g2, 2, cnt, flag, maxU, accD, payD, vsh, tid);
#pragma unroll
            for (int j = 0; j < 10; j++) vv[j] = vsh[j];
            double R0 = 0.0, R1 = 0.0;
#pragma unroll
            for (int j = 0; j < 10; j++) { R0 += (double)K0[j]*vv[j]; R1 += (double)K1[j]*vv[j]; }
            u0 = (1.0/NND) / R0;
            u1 = has1 ? (1.0/NND) / R1 : 0.0;
        }

        // ---- T += step * (u K v - T) ----
        float step = 2.f / (float)(c + 2);
        {
            float* Tr = Tt + (size_t)i0*10;
#pragma unroll
            for (int h = 0; h < 5; h++) {
                float a, b; t_load2(Tr + 2*h, a, b);
                float na = a + step*((float)(u0*(double)K0[2*h]  *vv[2*h])   - a);
                float nb = b + step*((float)(u0*(double)K0[2*h+1]*vv[2*h+1]) - b);
                t_store2(Tr + 2*h, na, nb);
            }
        }
        if (has1) {
            float* Tr = Tt + (size_t)i1*10;
#pragma unroll
            for (int h = 0; h < 5; h++) {
                float a, b; t_load2(Tr + 2*h, a, b);
                float na = a + step*((float)(u1*(double)K1[2*h]  *vv[2*h])   - a);
                float nb = b + step*((float)(u1*(double)K1[2*h+1]*vv[2*h+1]) - b);
                t_store2(Tr + 2*h, na, nb);
            }
        }
        __syncthreads();   // drain stores before arrival
        g_arrive_spin(t, c*32 + 32, 0, cnt, flag, maxU, accD, payD, vsh, tid);
    }

    // ---- final distance: 0.5<M,T> + 0.5<tens(T),T> ----
    double msum = 0.0, tsum = 0.0;
    {
        float L[10];
#pragma unroll
        for (int j = 0; j < 10; j++) L[j] = 0.f;
        for (int e = e00; e < e01; e++) {
            const float* Tk = Tt + (size_t)csrD[e]*10;
#pragma unroll
            for (int h = 0; h < 5; h++) { float a, b; t_load2(Tk + 2*h, a, b); L[2*h]+=a; L[2*h+1]+=b; }
        }
        float Tv[10];
#pragma unroll
        for (int h = 0; h < 5; h++) t_load2(Tt + (size_t)i0*10 + 2*h, Tv[2*h], Tv[2*h+1]);
#pragma unroll
        for (int j = 0; j < 10; j++) {
            float s = 0.f;
#pragma unroll
            for (int k = 0; k < 10; k++) s += L[k]*tC2[j*10+k];
            float ts = c1_0 + c2r[j] - s;
            msum += (double)(m0[j]*Tv[j]);
            tsum += (double)(ts*Tv[j]);
        }
    }
    if (has1) {
        float L[10];
#pragma unroll
        for (int j = 0; j < 10; j++) L[j] = 0.f;
        for (int e = e10; e < e11; e++) {
            const float* Tk = Tt + (size_t)csrD[e]*10;
#pragma unroll
            for (int h = 0; h < 5; h++) { float a, b; t_load2(Tk + 2*h, a, b); L[2*h]+=a; L[2*h+1]+=b; }
        }
        float Tv[10];
#pragma unroll
        for (int h = 0; h < 5; h++) t_load2(Tt + (size_t)i1*10 + 2*h, Tv[2*h], Tv[2*h+1]);
#pragma unroll
        for (int j = 0; j < 10; j++) {
            float s = 0.f;
#pragma unroll
            for (int k = 0; k < 10; k++) s += L[k]*tC2[j*10+k];
            float ts = c1_1 + c2r[j] - s;
            msum += (double)(m1[j]*Tv[j]);
            tsum += (double)(ts*Tv[j]);
        }
    }
    red[0][tid] = msum; red[1][tid] = tsum;
    __syncthreads();
    for (int off = 256; off; off >>= 1) {
        if (tid < off) { red[0][tid] += red[0][tid+off]; red[1][tid] += red[1][tid+off]; }
        __syncthreads();
    }
    if (tid == 0) { atomicAdd(&dd[2*t], red[0][0]); atomicAdd(&dd[2*t+1], red[1][0]); }
}

// ---------------- output head ----------------

__global__ void k_out(const double* __restrict__ dd, const float* __restrict__ Wlin,
                      const float* __restrict__ blin, float* __restrict__ out) {
    int tid = threadIdx.x;
    __shared__ float ds[NT];
    if (tid < NT) ds[tid] = 0.5f * (float)(dd[2 * tid] + dd[2 * tid + 1]);
    __syncthreads();
    if (tid < NC) {
        float o = blin[tid];
#pragma unroll
        for (int t = 0; t < NT; t++) o += ds[t] * Wlin[t * NC + tid];
        out[tid] = o;
    }
}

// ---------------- host ----------------

extern "C" void kernel_launch(void* const* d_in, const int* in_sizes, int n_in,
                              void* d_out, int out_size, void* d_ws, size_t ws_size,
                              hipStream_t stream) {
    const float* x    = (const float*)d_in[0];
    const int*   ei   = (const int*)d_in[1];
    const int*   src  = ei;
    const int*   dst  = ei + NE;
    const float* W1   = (const float*)d_in[2];
    const float* b1   = (const float*)d_in[3];
    const float* W2   = (const float*)d_in[4];
    const float* b2   = (const float*)d_in[5];
    const float* tpl  = (const float*)d_in[6];
    const float* tplF = (const float*)d_in[7];
    const float* Wlin = (const float*)d_in[8];
    const float* blin = (const float*)d_in[9];
    float* out = (float*)d_out;

    char* w = (char*)d_ws;
    size_t off = 0;
    auto alloc = [&](size_t b) -> char* {
        off = (off + 255) & ~(size_t)255;
        char* p = w + off; off += b; return p;
    };
    float* bufA = (float*)alloc((size_t)NND * NH * 4);
    float* bufB = (float*)alloc((size_t)NND * NH * 4);
    float* bufH = (float*)alloc((size_t)NND * NF * 4);
    float* Mm   = (float*)alloc((size_t)NT * NMAT * 4);
    float* T    = (float*)alloc((size_t)NT * NMAT * 4);
    // --- zero group (one memset) ---
    int* cntD = (int*)alloc((size_t)NND * 4);
    int* cntS = (int*)alloc((size_t)NND * 4);
    int* cur1 = (int*)alloc((size_t)NND * 4);
    int* cur2 = (int*)alloc((size_t)NND * 4);
    double* dd = (double*)alloc((size_t)NT * 2 * 8);
    int* cnt  = (int*)alloc((size_t)NT * SPAD * 4);
    int* flag = (int*)alloc((size_t)NT * SPAD * 4);
    unsigned* maxU = (unsigned*)alloc((size_t)NT * NGENS * 4);
    double* accD = (double*)alloc((size_t)NT * NGENS * 16 * 8);
    double* payD = (double*)alloc((size_t)NT * NGENS * 16 * 8);
    char* zend = w + off;
    // --- rest ---
    unsigned* bitmap = (unsigned*)alloc((size_t)781250 * 4);
    int* rpD  = (int*)alloc((size_t)(NND + 1) * 4);
    int* rpS  = (int*)alloc((size_t)(NND + 1) * 4);
    int* csrS = (int*)alloc((size_t)NE * 4);
    float* csrC = (float*)alloc((size_t)NE * 4);
    int* csrD2 = (int*)alloc((size_t)NE * 4);
    unsigned char* keep = (unsigned char*)alloc((size_t)NE);
    float* dinv  = (float*)alloc((size_t)NND * 4);
    float* c1row = (float*)alloc((size_t)NND * 4);
    float* sx    = (float*)alloc((size_t)NND * 4);
    float* sF    = (float*)alloc((size_t)100 * 4);
    float* c2row = (float*)alloc((size_t)100 * 4);

    hipMemsetAsync(cntD, 0, (size_t)(zend - (char*)cntD), stream);
    hipMemsetAsync(bitmap, 0, (size_t)781250 * 4, stream);

    // graph prep
    k_count<<<625, 256, 0, stream>>>(dst, cntD);
    k_dinv<<<20, 256, 0, stream>>>(cntD, dinv);
    k_exscan<<<1, 1024, 0, stream>>>(cntD, rpD, NND);
    k_scatter_dst<<<625, 256, 0, stream>>>(src, dst, rpD, cur1, csrS, csrC, dinv);

    // GCN
    k_gemm<<<dim3(NH / 64, (NND + 63) / 64), 256, 0, stream>>>(x, W1, bufA, NND, NH, NF);
    k_aggregate<<<NND, NH, 0, stream>>>(bufA, b1, bufB, rpD, csrS, csrC, dinv, 1);
    k_gemm<<<dim3(NF / 64, (NND + 63) / 64), 256, 0, stream>>>(bufB, W2, bufA, NND, NF, NH);
    k_aggregate<<<NND, NF, 0, stream>>>(bufA, b2, bufH, rpD, csrS, csrC, dinv, 0);

    // dedup adjacency + CSR by src
    k_dedup<<<625, 256, 0, stream>>>(src, dst, bitmap, cntS, keep);
    k_exscan<<<1, 1024, 0, stream>>>(cntS, rpS, NND);
    k_scatter_src<<<625, 256, 0, stream>>>(src, dst, keep, rpS, cur2, csrD2);

    // FGW prep
    k_prep_nodes<<<20, 256, 0, stream>>>(cntS, bufH, c1row, sx);
    k_prep_tpl<<<1, 128, 0, stream>>>(tpl, tplF, c2row, sF);
    k_M<<<NND, 128, 0, stream>>>(bufH, tplF, sx, sF, Mm);
    k_Tinit<<<1954, 256, 0, stream>>>(T);

    // fused CG + Sinkhorn + final distance (persistent, 80 co-resident blocks)
    k_fgw<<<NT * BPT, 512, 0, stream>>>(Mm, T, c1row, c2row, tpl, rpS, csrD2,
                                        cnt, flag, maxU, accD, payD, dd);

    k_out<<<1, 64, 0, stream>>>(dd, Wlin, blin, out);
}

// Round 3
// 1107.387 us; speedup vs baseline: 1.7626x; 1.7626x over previous
//
#include <hip/hip_runtime.h>
#include <cstdint>

#define NND 5000
#define NE 160000
#define NF 128
#define NH 256
#define NT 10
#define MT 10
#define NC 8
#define NMAT (NND*MT)      // 50000 per template
#define CG_ITERS 5
#define SINK_IT 30

// ---------------- graph prep ----------------

__global__ void k_count(const int* __restrict__ dst, int* __restrict__ cnt) {
    for (int e = blockIdx.x*blockDim.x + threadIdx.x; e < NE; e += gridDim.x*blockDim.x)
        atomicAdd(&cnt[dst[e]], 1);
}

__global__ void k_dinv(const int* __restrict__ cnt, float* __restrict__ dinv) {
    for (int v = blockIdx.x*blockDim.x + threadIdx.x; v < NND; v += gridDim.x*blockDim.x)
        dinv[v] = rsqrtf((float)(cnt[v] + 1));   // +1 self loop; always >= 1
}

__global__ void k_exscan(const int* __restrict__ cnt, int* __restrict__ rp, int n) {
    const int T = 1024;
    int tid = threadIdx.x;
    int C = (n + T - 1) / T;
    int begin = tid * C, end = begin + C; if (end > n) end = n; if (begin > n) begin = n;
    int s = 0;
    for (int i = begin; i < end; i++) s += cnt[i];
    __shared__ int part[1024];
    part[tid] = s; __syncthreads();
    for (int off = 1; off < T; off <<= 1) {
        int v = (tid >= off) ? part[tid - off] : 0;
        __syncthreads();
        part[tid] += v;
        __syncthreads();
    }
    int run = part[tid] - s;   // exclusive
    for (int i = begin; i < end; i++) { rp[i] = run; run += cnt[i]; }
    if (tid == T - 1) rp[n] = part[T - 1];
}

__global__ void k_scatter_dst(const int* __restrict__ src, const int* __restrict__ dst,
                              const int* __restrict__ rp, int* __restrict__ cur,
                              int* __restrict__ csrS, float* __restrict__ csrC,
                              const float* __restrict__ dinv) {
    for (int e = blockIdx.x*blockDim.x + threadIdx.x; e < NE; e += gridDim.x*blockDim.x) {
        int s = src[e], d = dst[e];
        int pos = rp[d] + atomicAdd(&cur[d], 1);
        csrS[pos] = s;
        csrC[pos] = dinv[s] * dinv[d];
    }
}

__global__ void k_dedup(const int* __restrict__ src, const int* __restrict__ dst,
                        unsigned* __restrict__ bitmap, int* __restrict__ cntS,
                        unsigned char* __restrict__ keep) {
    for (int e = blockIdx.x*blockDim.x + threadIdx.x; e < NE; e += gridDim.x*blockDim.x) {
        int s = src[e], d = dst[e];
        int key = s * NND + d;
        unsigned bit = 1u << (key & 31);
        unsigned old = atomicOr(&bitmap[key >> 5], bit);
        if (!(old & bit)) { keep[e] = 1; atomicAdd(&cntS[s], 1); }
        else keep[e] = 0;
    }
}

__global__ void k_scatter_src(const int* __restrict__ src, const int* __restrict__ dst,
                              const unsigned char* __restrict__ keep,
                              const int* __restrict__ rp, int* __restrict__ cur,
                              int* __restrict__ csrD) {
    for (int e = blockIdx.x*blockDim.x + threadIdx.x; e < NE; e += gridDim.x*blockDim.x) {
        if (keep[e]) {
            int s = src[e];
            int pos = rp[s] + atomicAdd(&cur[s], 1);
            csrD[pos] = dst[e];
        }
    }
}

// ---------------- GCN ----------------

__global__ __launch_bounds__(256) void k_gemm(const float* __restrict__ A,
                                              const float* __restrict__ B,
                                              float* __restrict__ C, int M, int N, int K) {
    const int BM = 64, BN = 64, BK = 16;
    __shared__ float As[BK][BM + 1];
    __shared__ float Bs[BK][BN];
    int tid = threadIdx.x;
    int row0 = blockIdx.y * BM, col0 = blockIdx.x * BN;
    int tx = tid % 16, ty = tid / 16;
    float acc[4][4] = {};
    for (int k0 = 0; k0 < K; k0 += BK) {
#pragma unroll
        for (int l = 0; l < 4; l++) {
            int idx = tid + l * 256;
            int r = idx / BK, kk = idx % BK;
            int gr = row0 + r;
            As[kk][r] = (gr < M) ? A[(size_t)gr * K + k0 + kk] : 0.f;
        }
#pragma unroll
        for (int l = 0; l < 4; l++) {
            int idx = tid + l * 256;
            int kk = idx / BN, c = idx % BN;
            Bs[kk][c] = B[(size_t)(k0 + kk) * N + col0 + c];
        }
        __syncthreads();
#pragma unroll
        for (int kk = 0; kk < BK; kk++) {
            float a[4], b[4];
#pragma unroll
            for (int i = 0; i < 4; i++) a[i] = As[kk][ty * 4 + i];
#pragma unroll
            for (int j = 0; j < 4; j++) b[j] = Bs[kk][tx * 4 + j];
#pragma unroll
            for (int i = 0; i < 4; i++)
#pragma unroll
                for (int j = 0; j < 4; j++) acc[i][j] += a[i] * b[j];
        }
        __syncthreads();
    }
#pragma unroll
    for (int i = 0; i < 4; i++) {
        int gr = row0 + ty * 4 + i;
        if (gr < M) {
#pragma unroll
            for (int j = 0; j < 4; j++)
                C[(size_t)gr * N + col0 + tx * 4 + j] = acc[i][j];
        }
    }
}

__global__ void k_aggregate(const float* __restrict__ hin, const float* __restrict__ bias,
                            float* __restrict__ hout, const int* __restrict__ rp,
                            const int* __restrict__ csrS, const float* __restrict__ csrC,
                            const float* __restrict__ dinv, int relu) {
    int v = blockIdx.x;
    int f = threadIdx.x;
    int F = blockDim.x;
    float dv = dinv[v];
    float acc = hin[(size_t)v * F + f] * dv * dv;   // structural self-loop
    int e0 = rp[v], e1 = rp[v + 1];
    for (int e = e0; e < e1; e++)
        acc += hin[(size_t)csrS[e] * F + f] * csrC[e];
    acc += bias[f];
    if (relu) acc = fmaxf(acc, 0.f);
    hout[(size_t)v * F + f] = acc;
}

// ---------------- FGW prep ----------------

__global__ void k_prep_nodes(const int* __restrict__ cntS, const float* __restrict__ h,
                             float* __restrict__ c1row, float* __restrict__ sx) {
    for (int i = blockIdx.x*blockDim.x + threadIdx.x; i < NND; i += gridDim.x*blockDim.x) {
        c1row[i] = (float)cntS[i] * (1.f / NND);
        float s = 0.f;
        for (int f = 0; f < NF; f++) { float v = h[(size_t)i * NF + f]; s += v * v; }
        sx[i] = s;
    }
}

__global__ void k_prep_tpl(const float* __restrict__ tpl, const float* __restrict__ tplF,
                           float* __restrict__ c2row, float* __restrict__ sF) {
    int c = threadIdx.x;
    if (c < NT * MT) {
        int t = c / MT, j = c % MT;
        float s = 0.f;
        for (int k = 0; k < MT; k++) { float v = tpl[t * 100 + j * 10 + k]; s += v * v; }
        c2row[c] = s * (1.f / MT);
        float sf = 0.f;
        for (int f = 0; f < NF; f++) { float v = tplF[(size_t)c * NF + f]; sf += v * v; }
        sF[c] = sf;
    }
}

__global__ void k_M(const float* __restrict__ h, const float* __restrict__ tplF,
                    const float* __restrict__ sx, const float* __restrict__ sF,
                    float* __restrict__ Mout) {
    int i = blockIdx.x;
    __shared__ float hrow[NF];
    hrow[threadIdx.x] = h[(size_t)i * NF + threadIdx.x];
    __syncthreads();
    int c = threadIdx.x;
    if (c < NT * MT) {
        const float* Fc = tplF + (size_t)c * NF;
        float dot = 0.f;
        for (int f = 0; f < NF; f++) dot += hrow[f] * Fc[f];
        int t = c / MT, j = c % MT;
        Mout[(size_t)t * NMAT + (size_t)i * MT + j] = sx[i] + sF[c] - 2.f * dot;
    }
}

__global__ void k_Tinit(float* __restrict__ T) {
    for (int idx = blockIdx.x*blockDim.x + threadIdx.x; idx < NT * NMAT; idx += gridDim.x*blockDim.x)
        T[idx] = 1.f / (float)NMAT;
}

// ---------------- CG iteration ----------------

__global__ __launch_bounds__(256) void k_grad(const float* __restrict__ T, const float* __restrict__ Mm,
                                              const float* __restrict__ c1row, const float* __restrict__ c2row,
                                              const float* __restrict__ tpl,
                                              const int* __restrict__ rpS, const int* __restrict__ csrD,
                                              float* __restrict__ G, unsigned* __restrict__ scaleBits) {
    int t = blockIdx.y;
    int tid = threadIdx.x;
    __shared__ float tC2[100];
    if (tid < 100) tC2[tid] = 2.f * tpl[t * 100 + tid];
    __syncthreads();
    int i = blockIdx.x * 256 + tid;
    float amax = 0.f;
    if (i < NND) {
        const float* Tt = T + (size_t)t * NMAT;
        const float* Mt = Mm + (size_t)t * NMAT;
        float* Gt = G + (size_t)t * NMAT;
        float L[MT];
#pragma unroll
        for (int j = 0; j < MT; j++) L[j] = 0.f;
        int e0 = rpS[i], e1 = rpS[i + 1];
        for (int e = e0; e < e1; e++) {
            int k = csrD[e];
            const float* Tk = Tt + (size_t)k * MT;
#pragma unroll
            for (int j = 0; j < MT; j++) L[j] += Tk[j];
        }
        float c1 = c1row[i];
#pragma unroll
        for (int j = 0; j < MT; j++) {
            float s = 0.f;
#pragma unroll
            for (int k = 0; k < MT; k++) s += L[k] * tC2[j * 10 + k];
            // grad = (1-a)M + 2a*(constC - C1 T (2C2)^T), a=0.5
            float g = 0.5f * Mt[(size_t)i * MT + j] + (c1 + c2row[t * 10 + j] - s);
            Gt[(size_t)i * MT + j] = g;
            amax = fmaxf(amax, fabsf(g));
        }
    }
    __shared__ float red[256];
    red[tid] = amax; __syncthreads();
    for (int off = 128; off > 0; off >>= 1) {
        if (tid < off) red[tid] = fmaxf(red[tid], red[tid + off]);
        __syncthreads();
    }
    if (tid == 0) atomicMax(&scaleBits[t], __float_as_uint(red[0]));
}

// fast f64 reciprocal: v_rcp_f64 + 2 Newton steps (relative err ~2^-58)
__device__ __forceinline__ double drcp(double d) {
#if __has_builtin(__builtin_amdgcn_rcp)
    double r = __builtin_amdgcn_rcp(d);
    double e = __builtin_fma(-d, r, 1.0);
    r = __builtin_fma(r, e, r);
    e = __builtin_fma(-d, r, 1.0);
    r = __builtin_fma(r, e, r);
    return r;
#else
    return 1.0 / d;
#endif
}

// one block per template; scaling-form sinkhorn, K in f32 regs, u/v in f64.
// ONE barrier per iteration: double-buffered wave partials (wred[p]) + every
// thread redundantly combines the 8 partials and computes all 10 v_j itself.
__global__ __launch_bounds__(512, 1) void k_sinkhorn(const float* __restrict__ G,
                                                     const float* __restrict__ scale,
                                                     float* __restrict__ T, float step) {
    int t = blockIdx.x;
    int tid = threadIdx.x;
    int lane = tid & 63, w = tid >> 6;
    float sc = scale[t] + 1e-9f;
    float inv = -1.f / (0.02f * sc);
    const float* Gt = G + (size_t)t * NMAT;
    float* Tt = T + (size_t)t * NMAT;

    float Kf[10][10];
    double u[10];
#pragma unroll
    for (int r = 0; r < 10; r++) {
        int i = tid + r * 512;
        u[r] = (i < NND) ? 1.0 : 0.0;
        if (i < NND) {
            const float2* Gr = (const float2*)(Gt + (size_t)i * 10);
#pragma unroll
            for (int h = 0; h < 5; h++) {
                float2 g = Gr[h];
                Kf[r][2*h]   = __expf(g.x * inv);
                Kf[r][2*h+1] = __expf(g.y * inv);
            }
        } else {
#pragma unroll
            for (int j = 0; j < 10; j++) Kf[r][j] = 0.f;
        }
    }

    __shared__ double wred[2][8][10];   // [parity][wave][col]
    double vv[10];

    for (int it = 0; it < SINK_IT; it++) {
        int p = it & 1;
        double S[10];
#pragma unroll
        for (int j = 0; j < 10; j++) S[j] = 0.0;
#pragma unroll
        for (int r = 0; r < 10; r++) {
            double ur = u[r];
#pragma unroll
            for (int j = 0; j < 10; j++) S[j] += (double)Kf[r][j] * ur;
        }
        // wave-level reduce (64 lanes)
#pragma unroll
        for (int off = 32; off; off >>= 1) {
#pragma unroll
            for (int j = 0; j < 10; j++) S[j] += __shfl_down(S[j], off);
        }
        if (lane == 0) {
#pragma unroll
            for (int j = 0; j < 10; j++) wred[p][w][j] = S[j];
        }
        __syncthreads();
        // every thread combines 8 wave partials (LDS broadcast, b128 reads)
        double cs[10];
#pragma unroll
        for (int j = 0; j < 10; j++) cs[j] = 0.0;
#pragma unroll
        for (int q = 0; q < 8; q++) {
            const double2* wp = (const double2*)(&wred[p][q][0]);
#pragma unroll
            for (int h = 0; h < 5; h++) {
                double2 d = wp[h];
                cs[2*h] += d.x; cs[2*h+1] += d.y;
            }
        }
#pragma unroll
        for (int j = 0; j < 10; j++) vv[j] = 0.1 * drcp(cs[j]);   // v = q/(K^T u)
#pragma unroll
        for (int r = 0; r < 10; r++) {
            double R = 0.0;
#pragma unroll
            for (int j = 0; j < 10; j++) R += (double)Kf[r][j] * vv[j];
            u[r] = (tid + r * 512 < NND) ? (1.0 / NND) * drcp(R) : 0.0;   // u = p/(K v)
        }
    }
    // T update: T += step*(u K v - T)
#pragma unroll
    for (int r = 0; r < 10; r++) {
        int i = tid + r * 512;
        if (i < NND) {
            double ur = u[r];
            float2* Tr = (float2*)(Tt + (size_t)i * 10);
#pragma unroll
            for (int h = 0; h < 5; h++) {
                float2 v = Tr[h];
                float na = v.x + step * ((float)(ur * (double)Kf[r][2*h]   * vv[2*h])   - v.x);
                float nb = v.y + step * ((float)(ur * (double)Kf[r][2*h+1] * vv[2*h+1]) - v.y);
                Tr[h] = make_float2(na, nb);
            }
        }
    }
}

// ---------------- final distance + head ----------------

__global__ __launch_bounds__(256) void k_final(const float* __restrict__ T, const float* __restrict__ Mm,
                                               const float* __restrict__ c1row, const float* __restrict__ c2row,
                                               const float* __restrict__ tpl,
                                               const int* __restrict__ rpS, const int* __restrict__ csrD,
                                               double* __restrict__ dd) {
    int t = blockIdx.y;
    int tid = threadIdx.x;
    __shared__ float tC2[100];
    if (tid < 100) tC2[tid] = 2.f * tpl[t * 100 + tid];
    __syncthreads();
    int i = blockIdx.x * 256 + tid;
    double msum = 0.0, tsum = 0.0;
    if (i < NND) {
        const float* Tt = T + (size_t)t * NMAT;
        const float* Mt = Mm + (size_t)t * NMAT;
        float L[MT];
#pragma unroll
        for (int j = 0; j < MT; j++) L[j] = 0.f;
        int e0 = rpS[i], e1 = rpS[i + 1];
        for (int e = e0; e < e1; e++) {
            int k = csrD[e];
            const float* Tk = Tt + (size_t)k * MT;
#pragma unroll
            for (int j = 0; j < MT; j++) L[j] += Tk[j];
        }
        float c1 = c1row[i];
#pragma unroll
        for (int j = 0; j < MT; j++) {
            float s = 0.f;
#pragma unroll
            for (int k = 0; k < MT; k++) s += L[k] * tC2[j * 10 + k];
            float ts = c1 + c2row[t * 10 + j] - s;
            float Tv = Tt[(size_t)i * MT + j];
            msum += (double)(Mt[(size_t)i * MT + j] * Tv);
            tsum += (double)(ts * Tv);
        }
    }
    __shared__ double r1[256], r2[256];
    r1[tid] = msum; r2[tid] = tsum; __syncthreads();
    for (int off = 128; off > 0; off >>= 1) {
        if (tid < off) { r1[tid] += r1[tid + off]; r2[tid] += r2[tid + off]; }
        __syncthreads();
    }
    if (tid == 0) { atomicAdd(&dd[t * 2], r1[0]); atomicAdd(&dd[t * 2 + 1], r2[0]); }
}

__global__ void k_out(const double* __restrict__ dd, const float* __restrict__ Wlin,
                      const float* __restrict__ blin, float* __restrict__ out) {
    int tid = threadIdx.x;
    __shared__ float ds[NT];
    if (tid < NT) ds[tid] = 0.5f * (float)(dd[2 * tid] + dd[2 * tid + 1]);
    __syncthreads();
    if (tid < NC) {
        float o = blin[tid];
#pragma unroll
        for (int t = 0; t < NT; t++) o += ds[t] * Wlin[t * NC + tid];
        out[tid] = o;
    }
}

// ---------------- host ----------------

extern "C" void kernel_launch(void* const* d_in, const int* in_sizes, int n_in,
                              void* d_out, int out_size, void* d_ws, size_t ws_size,
                              hipStream_t stream) {
    const float* x    = (const float*)d_in[0];
    const int*   ei   = (const int*)d_in[1];
    const int*   src  = ei;
    const int*   dst  = ei + NE;
    const float* W1   = (const float*)d_in[2];
    const float* b1   = (const float*)d_in[3];
    const float* W2   = (const float*)d_in[4];
    const float* b2   = (const float*)d_in[5];
    const float* tpl  = (const float*)d_in[6];
    const float* tplF = (const float*)d_in[7];
    const float* Wlin = (const float*)d_in[8];
    const float* blin = (const float*)d_in[9];
    float* out = (float*)d_out;

    char* w = (char*)d_ws;
    size_t off = 0;
    auto alloc = [&](size_t b) -> char* {
        off = (off + 255) & ~(size_t)255;
        char* p = w + off; off += b; return p;
    };
    float* bufA = (float*)alloc((size_t)NND * NH * 4);
    float* bufB = (float*)alloc((size_t)NND * NH * 4);
    float* bufH = (float*)alloc((size_t)NND * NF * 4);
    float* Mm   = (float*)alloc((size_t)NT * NMAT * 4);
    float* T    = (float*)alloc((size_t)NT * NMAT * 4);
    float* G    = (float*)alloc((size_t)NT * NMAT * 4);
    // --- zero group (one memset) ---
    int* cntD = (int*)alloc((size_t)NND * 4);
    int* cntS = (int*)alloc((size_t)NND * 4);
    int* cur1 = (int*)alloc((size_t)NND * 4);
    int* cur2 = (int*)alloc((size_t)NND * 4);
    double* dd = (double*)alloc((size_t)NT * 2 * 8);
    char* zend = w + off;
    // --- rest ---
    unsigned* scaleBits = (unsigned*)alloc((size_t)NT * 4);
    unsigned* bitmap = (unsigned*)alloc((size_t)781250 * 4);
    int* rpD  = (int*)alloc((size_t)(NND + 1) * 4);
    int* rpS  = (int*)alloc((size_t)(NND + 1) * 4);
    int* csrS = (int*)alloc((size_t)NE * 4);
    float* csrC = (float*)alloc((size_t)NE * 4);
    int* csrD2 = (int*)alloc((size_t)NE * 4);
    unsigned char* keep = (unsigned char*)alloc((size_t)NE);
    float* dinv  = (float*)alloc((size_t)NND * 4);
    float* c1row = (float*)alloc((size_t)NND * 4);
    float* sx    = (float*)alloc((size_t)NND * 4);
    float* sF    = (float*)alloc((size_t)100 * 4);
    float* c2row = (float*)alloc((size_t)100 * 4);

    hipMemsetAsync(cntD, 0, (size_t)(zend - (char*)cntD), stream);
    hipMemsetAsync(bitmap, 0, (size_t)781250 * 4, stream);

    // graph prep
    k_count<<<625, 256, 0, stream>>>(dst, cntD);
    k_dinv<<<20, 256, 0, stream>>>(cntD, dinv);
    k_exscan<<<1, 1024, 0, stream>>>(cntD, rpD, NND);
    k_scatter_dst<<<625, 256, 0, stream>>>(src, dst, rpD, cur1, csrS, csrC, dinv);

    // GCN
    k_gemm<<<dim3(NH / 64, (NND + 63) / 64), 256, 0, stream>>>(x, W1, bufA, NND, NH, NF);
    k_aggregate<<<NND, NH, 0, stream>>>(bufA, b1, bufB, rpD, csrS, csrC, dinv, 1);
    k_gemm<<<dim3(NF / 64, (NND + 63) / 64), 256, 0, stream>>>(bufB, W2, bufA, NND, NF, NH);
    k_aggregate<<<NND, NF, 0, stream>>>(bufA, b2, bufH, rpD, csrS, csrC, dinv, 0);

    // dedup adjacency + CSR by src
    k_dedup<<<625, 256, 0, stream>>>(src, dst, bitmap, cntS, keep);
    k_exscan<<<1, 1024, 0, stream>>>(cntS, rpS, NND);
    k_scatter_src<<<625, 256, 0, stream>>>(src, dst, keep, rpS, cur2, csrD2);

    // FGW prep
    k_prep_nodes<<<20, 256, 0, stream>>>(cntS, bufH, c1row, sx);
    k_prep_tpl<<<1, 128, 0, stream>>>(tpl, tplF, c2row, sF);
    k_M<<<NND, 128, 0, stream>>>(bufH, tplF, sx, sF, Mm);
    k_Tinit<<<1954, 256, 0, stream>>>(T);

    // conditional gradient loop
    for (int t = 0; t < CG_ITERS; t++) {
        hipMemsetAsync(scaleBits, 0, NT * 4, stream);
        k_grad<<<dim3(20, NT), 256, 0, stream>>>(T, Mm, c1row, c2row, tpl, rpS, csrD2, G, scaleBits);
        float step = 2.f / (float)(t + 2);
        k_sinkhorn<<<NT, 512, 0, stream>>>(G, (const float*)scaleBits, T, step);
    }

    // final distances + linear head
    k_final<<<dim3(20, NT), 256, 0, stream>>>(T, Mm, c1row, c2row, tpl, rpS, csrD2, dd);
    k_out<<<1, 64, 0, stream>>>(dd, Wlin, blin, out);
}

// Round 4
// 702.169 us; speedup vs baseline: 2.7798x; 1.5771x over previous
//
#include <hip/hip_runtime.h>
#include <cstdint>

#define NND 5000
#define NE 160000
#define NF 128
#define NH 256
#define NT 10
#define MT 10
#define NC 8
#define NMAT (NND*MT)      // 50000 per template
#define CG_ITERS 5
#define SINK_IT 30

// ---------------- graph prep (merged) ----------------

// pass 1 over edges: dst-degree count + dedup bitmap + src-degree of distinct edges
__global__ void k_edge1(const int* __restrict__ src, const int* __restrict__ dst,
                        int* __restrict__ cntD, unsigned* __restrict__ bitmap,
                        int* __restrict__ cntS, unsigned char* __restrict__ keep) {
    for (int e = blockIdx.x*blockDim.x + threadIdx.x; e < NE; e += gridDim.x*blockDim.x) {
        int s = src[e], d = dst[e];
        atomicAdd(&cntD[d], 1);
        int key = s * NND + d;
        unsigned bit = 1u << (key & 31);
        unsigned old = atomicOr(&bitmap[key >> 5], bit);
        if (!(old & bit)) { keep[e] = 1; atomicAdd(&cntS[s], 1); }
        else keep[e] = 0;
    }
}

// block 0: cntD -> rpD (+ dinv); block 1: cntS -> rpS
__global__ void k_exscan2(const int* __restrict__ cntD, int* __restrict__ rpD,
                          float* __restrict__ dinv,
                          const int* __restrict__ cntS, int* __restrict__ rpS) {
    const int T = 1024;
    const int* cnt = blockIdx.x ? cntS : cntD;
    int* rp = blockIdx.x ? rpS : rpD;
    int tid = threadIdx.x;
    int C = (NND + T - 1) / T;
    int begin = tid * C, end = begin + C; if (end > NND) end = NND; if (begin > NND) begin = NND;
    int s = 0;
    for (int i = begin; i < end; i++) s += cnt[i];
    __shared__ int part[1024];
    part[tid] = s; __syncthreads();
    for (int off = 1; off < T; off <<= 1) {
        int v = (tid >= off) ? part[tid - off] : 0;
        __syncthreads();
        part[tid] += v;
        __syncthreads();
    }
    int run = part[tid] - s;   // exclusive
    for (int i = begin; i < end; i++) { rp[i] = run; run += cnt[i]; }
    if (tid == T - 1) rp[NND] = part[T - 1];
    if (blockIdx.x == 0)
        for (int i = begin; i < end; i++) dinv[i] = rsqrtf((float)(cnt[i] + 1));
}

// pass 2 over edges: scatter into CSR-by-dst (weighted) and CSR-by-src (distinct)
__global__ void k_scatter2(const int* __restrict__ src, const int* __restrict__ dst,
                           const unsigned char* __restrict__ keep,
                           const int* __restrict__ rpD, int* __restrict__ cur1,
                           int* __restrict__ csrS, float* __restrict__ csrC,
                           const float* __restrict__ dinv,
                           const int* __restrict__ rpS, int* __restrict__ cur2,
                           int* __restrict__ csrD) {
    for (int e = blockIdx.x*blockDim.x + threadIdx.x; e < NE; e += gridDim.x*blockDim.x) {
        int s = src[e], d = dst[e];
        int pos = rpD[d] + atomicAdd(&cur1[d], 1);
        csrS[pos] = s;
        csrC[pos] = dinv[s] * dinv[d];
        if (keep[e]) {
            int p2 = rpS[s] + atomicAdd(&cur2[s], 1);
            csrD[p2] = d;
        }
    }
}

// ---------------- GCN ----------------

__global__ __launch_bounds__(256) void k_gemm(const float* __restrict__ A,
                                              const float* __restrict__ B,
                                              float* __restrict__ C, int M, int N, int K) {
    const int BM = 64, BN = 64, BK = 16;
    __shared__ float As[BK][BM + 1];
    __shared__ float Bs[BK][BN];
    int tid = threadIdx.x;
    int row0 = blockIdx.y * BM, col0 = blockIdx.x * BN;
    int tx = tid % 16, ty = tid / 16;
    float acc[4][4] = {};
    for (int k0 = 0; k0 < K; k0 += BK) {
#pragma unroll
        for (int l = 0; l < 4; l++) {
            int idx = tid + l * 256;
            int r = idx / BK, kk = idx % BK;
            int gr = row0 + r;
            As[kk][r] = (gr < M) ? A[(size_t)gr * K + k0 + kk] : 0.f;
        }
#pragma unroll
        for (int l = 0; l < 4; l++) {
            int idx = tid + l * 256;
            int kk = idx / BN, c = idx % BN;
            Bs[kk][c] = B[(size_t)(k0 + kk) * N + col0 + c];
        }
        __syncthreads();
#pragma unroll
        for (int kk = 0; kk < BK; kk++) {
            float a[4], b[4];
#pragma unroll
            for (int i = 0; i < 4; i++) a[i] = As[kk][ty * 4 + i];
#pragma unroll
            for (int j = 0; j < 4; j++) b[j] = Bs[kk][tx * 4 + j];
#pragma unroll
            for (int i = 0; i < 4; i++)
#pragma unroll
                for (int j = 0; j < 4; j++) acc[i][j] += a[i] * b[j];
        }
        __syncthreads();
    }
#pragma unroll
    for (int i = 0; i < 4; i++) {
        int gr = row0 + ty * 4 + i;
        if (gr < M) {
#pragma unroll
            for (int j = 0; j < 4; j++)
                C[(size_t)gr * N + col0 + tx * 4 + j] = acc[i][j];
        }
    }
}

__global__ void k_aggregate(const float* __restrict__ hin, const float* __restrict__ bias,
                            float* __restrict__ hout, const int* __restrict__ rp,
                            const int* __restrict__ csrS, const float* __restrict__ csrC,
                            const float* __restrict__ dinv, int relu) {
    int v = blockIdx.x;
    int f = threadIdx.x;
    int F = blockDim.x;
    float dv = dinv[v];
    float acc = hin[(size_t)v * F + f] * dv * dv;   // structural self-loop
    int e0 = rp[v], e1 = rp[v + 1];
    for (int e = e0; e < e1; e++)
        acc += hin[(size_t)csrS[e] * F + f] * csrC[e];
    acc += bias[f];
    if (relu) acc = fmaxf(acc, 0.f);
    hout[(size_t)v * F + f] = acc;
}

// ---------------- FGW prep ----------------

// node sums + (block 0) template sums
__global__ void k_prepnt(const int* __restrict__ cntS, const float* __restrict__ h,
                         float* __restrict__ c1row, float* __restrict__ sx,
                         const float* __restrict__ tpl, const float* __restrict__ tplF,
                         float* __restrict__ c2row, float* __restrict__ sF) {
    for (int i = blockIdx.x*blockDim.x + threadIdx.x; i < NND; i += gridDim.x*blockDim.x) {
        c1row[i] = (float)cntS[i] * (1.f / NND);
        float s = 0.f;
        for (int f = 0; f < NF; f++) { float v = h[(size_t)i * NF + f]; s += v * v; }
        sx[i] = s;
    }
    if (blockIdx.x == 0 && threadIdx.x < NT * MT) {
        int c = threadIdx.x;
        int t = c / MT, j = c % MT;
        float s = 0.f;
        for (int k = 0; k < MT; k++) { float v = tpl[t * 100 + j * 10 + k]; s += v * v; }
        c2row[c] = s * (1.f / MT);
        float sf = 0.f;
        for (int f = 0; f < NF; f++) { float v = tplF[(size_t)c * NF + f]; sf += v * v; }
        sF[c] = sf;
    }
}

__global__ void k_M(const float* __restrict__ h, const float* __restrict__ tplF,
                    const float* __restrict__ sx, const float* __restrict__ sF,
                    float* __restrict__ Mout) {
    int i = blockIdx.x;
    __shared__ float hrow[NF];
    hrow[threadIdx.x] = h[(size_t)i * NF + threadIdx.x];
    __syncthreads();
    int c = threadIdx.x;
    if (c < NT * MT) {
        const float* Fc = tplF + (size_t)c * NF;
        float dot = 0.f;
        for (int f = 0; f < NF; f++) dot += hrow[f] * Fc[f];
        int t = c / MT, j = c % MT;
        Mout[(size_t)t * NMAT + (size_t)i * MT + j] = sx[i] + sF[c] - 2.f * dot;
    }
}

__global__ void k_Tinit(float* __restrict__ T) {
    for (int idx = blockIdx.x*blockDim.x + threadIdx.x; idx < NT * NMAT; idx += gridDim.x*blockDim.x)
        T[idx] = 1.f / (float)NMAT;
}

// ---------------- CG iteration ----------------

__global__ __launch_bounds__(256) void k_grad(const float* __restrict__ T, const float* __restrict__ Mm,
                                              const float* __restrict__ c1row, const float* __restrict__ c2row,
                                              const float* __restrict__ tpl,
                                              const int* __restrict__ rpS, const int* __restrict__ csrD,
                                              float* __restrict__ G, unsigned* __restrict__ scaleBits) {
    int t = blockIdx.y;
    int tid = threadIdx.x;
    __shared__ float tC2[100];
    if (tid < 100) tC2[tid] = 2.f * tpl[t * 100 + tid];
    __syncthreads();
    int i = blockIdx.x * 256 + tid;
    float amax = 0.f;
    if (i < NND) {
        const float* Tt = T + (size_t)t * NMAT;
        const float* Mt = Mm + (size_t)t * NMAT;
        float* Gt = G + (size_t)t * NMAT;
        float L[MT];
#pragma unroll
        for (int j = 0; j < MT; j++) L[j] = 0.f;
        int e0 = rpS[i], e1 = rpS[i + 1];
        for (int e = e0; e < e1; e++) {
            int k = csrD[e];
            const float* Tk = Tt + (size_t)k * MT;
#pragma unroll
            for (int j = 0; j < MT; j++) L[j] += Tk[j];
        }
        float c1 = c1row[i];
#pragma unroll
        for (int j = 0; j < MT; j++) {
            float s = 0.f;
#pragma unroll
            for (int k = 0; k < MT; k++) s += L[k] * tC2[j * 10 + k];
            // grad = (1-a)M + 2a*(constC - C1 T (2C2)^T), a=0.5
            float g = 0.5f * Mt[(size_t)i * MT + j] + (c1 + c2row[t * 10 + j] - s);
            Gt[(size_t)i * MT + j] = g;
            amax = fmaxf(amax, fabsf(g));
        }
    }
    __shared__ float red[256];
    red[tid] = amax; __syncthreads();
    for (int off = 128; off > 0; off >>= 1) {
        if (tid < off) red[tid] = fmaxf(red[tid], red[tid + off]);
        __syncthreads();
    }
    if (tid == 0) atomicMax(&scaleBits[t], __float_as_uint(red[0]));
}

__device__ __forceinline__ float frcp(float x) {
#if __has_builtin(__builtin_amdgcn_rcpf)
    return __builtin_amdgcn_rcpf(x);   // v_rcp_f32, ~1 ulp
#else
    return 1.f / x;
#endif
}

// one block per template; all-f32 scaling-form sinkhorn.
// Range safety: |G*inv| <= 50 exactly (scale = max|G|), so K in [1.9e-22, 5.2e21]
// and all intermediates stay inside f32 (first-iter colsum <= 2.6e25).
// Column reduce via column-major LDS tree (no ds_bpermute butterfly).
__global__ __launch_bounds__(512, 1) void k_sinkhorn(const float* __restrict__ G,
                                                     const unsigned* __restrict__ scaleBits,
                                                     float* __restrict__ T, float step) {
    int t = blockIdx.x;
    int tid = threadIdx.x;
    float sc = __uint_as_float(scaleBits[t]) + 1e-9f;
    float inv = -1.f / (0.02f * sc);
    const float* Gt = G + (size_t)t * NMAT;
    float* Tt = T + (size_t)t * NMAT;

    __shared__ float Sa[10][516];   // column-major partials; 516 = pad (mod 32 = 4)
    __shared__ float Sb[10][33];    // level-2 partials, padded
    __shared__ float vbc[12];       // broadcast v

    float Kf[10][10];
    float u[10];
#pragma unroll
    for (int r = 0; r < 10; r++) {
        int i = tid + r * 512;
        if (i < NND) {
            u[r] = 1.f;
            const float2* Gr = (const float2*)(Gt + (size_t)i * 10);
#pragma unroll
            for (int h = 0; h < 5; h++) {
                float2 g = Gr[h];
                Kf[r][2*h]   = __expf(g.x * inv);
                Kf[r][2*h+1] = __expf(g.y * inv);
            }
        } else {
            u[r] = 0.f;
#pragma unroll
            for (int j = 0; j < 10; j++) Kf[r][j] = 0.f;
        }
    }

    float vv[10];
    int bj = tid % 10, bg = tid / 10;     // phase-B role (tid < 320)

    for (int it = 0; it < SINK_IT; it++) {
        // per-thread column partials over its 10 rows
        float S[10];
#pragma unroll
        for (int j = 0; j < 10; j++) S[j] = 0.f;
#pragma unroll
        for (int r = 0; r < 10; r++) {
            float ur = u[r];
#pragma unroll
            for (int j = 0; j < 10; j++) S[j] = fmaf(Kf[r][j], ur, S[j]);
        }
#pragma unroll
        for (int j = 0; j < 10; j++) Sa[j][tid] = S[j];   // conflict-free b32 writes
        __syncthreads();
        // level 1: 320 threads, each sums 16 consecutive floats of one column
        if (tid < 320) {
            const float4* p = (const float4*)&Sa[bj][bg * 16];
            float4 a = p[0], b = p[1], c = p[2], d = p[3];
            Sb[bj][bg] = ((a.x + a.y) + (a.z + a.w)) + ((b.x + b.y) + (b.z + b.w))
                       + ((c.x + c.y) + (c.z + c.w)) + ((d.x + d.y) + (d.z + d.w));
        }
        __syncthreads();
        // level 2: 10 threads finish 32 partials, publish v = q / colsum
        if (tid < 10) {
            const float* q = &Sb[tid][0];
            float s = 0.f;
#pragma unroll
            for (int g = 0; g < 32; g++) s += q[g];
            vbc[tid] = 0.1f * frcp(fmaxf(s, 1e-30f));
        }
        __syncthreads();
#pragma unroll
        for (int j = 0; j < 10; j++) vv[j] = vbc[j];      // broadcast reads
        // row update: u = p / (K v)
#pragma unroll
        for (int r = 0; r < 10; r++) {
            float R = 0.f;
#pragma unroll
            for (int j = 0; j < 10; j++) R = fmaf(Kf[r][j], vv[j], R);
            u[r] = (tid + r * 512 < NND) ? (2e-4f * frcp(fmaxf(R, 1e-30f))) : 0.f;
        }
    }

    // T += step * (u K v - T)
#pragma unroll
    for (int r = 0; r < 10; r++) {
        int i = tid + r * 512;
        if (i < NND) {
            float ur = u[r];
            float2* Tr = (float2*)(Tt + (size_t)i * 10);
#pragma unroll
            for (int h = 0; h < 5; h++) {
                float2 v = Tr[h];
                v.x += step * (ur * Kf[r][2*h]   * vv[2*h]   - v.x);
                v.y += step * (ur * Kf[r][2*h+1] * vv[2*h+1] - v.y);
                Tr[h] = v;
            }
        }
    }
}

// ---------------- final distance + head ----------------

__global__ __launch_bounds__(256) void k_final(const float* __restrict__ T, const float* __restrict__ Mm,
                                               const float* __restrict__ c1row, const float* __restrict__ c2row,
                                               const float* __restrict__ tpl,
                                               const int* __restrict__ rpS, const int* __restrict__ csrD,
                                               double* __restrict__ dd) {
    int t = blockIdx.y;
    int tid = threadIdx.x;
    __shared__ float tC2[100];
    if (tid < 100) tC2[tid] = 2.f * tpl[t * 100 + tid];
    __syncthreads();
    int i = blockIdx.x * 256 + tid;
    double msum = 0.0, tsum = 0.0;
    if (i < NND) {
        const float* Tt = T + (size_t)t * NMAT;
        const float* Mt = Mm + (size_t)t * NMAT;
        float L[MT];
#pragma unroll
        for (int j = 0; j < MT; j++) L[j] = 0.f;
        int e0 = rpS[i], e1 = rpS[i + 1];
        for (int e = e0; e < e1; e++) {
            int k = csrD[e];
            const float* Tk = Tt + (size_t)k * MT;
#pragma unroll
            for (int j = 0; j < MT; j++) L[j] += Tk[j];
        }
        float c1 = c1row[i];
#pragma unroll
        for (int j = 0; j < MT; j++) {
            float s = 0.f;
#pragma unroll
            for (int k = 0; k < MT; k++) s += L[k] * tC2[j * 10 + k];
            float ts = c1 + c2row[t * 10 + j] - s;
            float Tv = Tt[(size_t)i * MT + j];
            msum += (double)(Mt[(size_t)i * MT + j] * Tv);
            tsum += (double)(ts * Tv);
        }
    }
    __shared__ double r1[256], r2[256];
    r1[tid] = msum; r2[tid] = tsum; __syncthreads();
    for (int off = 128; off > 0; off >>= 1) {
        if (tid < off) { r1[tid] += r1[tid + off]; r2[tid] += r2[tid + off]; }
        __syncthreads();
    }
    if (tid == 0) { atomicAdd(&dd[t * 2], r1[0]); atomicAdd(&dd[t * 2 + 1], r2[0]); }
}

__global__ void k_out(const double* __restrict__ dd, const float* __restrict__ Wlin,
                      const float* __restrict__ blin, float* __restrict__ out) {
    int tid = threadIdx.x;
    __shared__ float ds[NT];
    if (tid < NT) ds[tid] = 0.5f * (float)(dd[2 * tid] + dd[2 * tid + 1]);
    __syncthreads();
    if (tid < NC) {
        float o = blin[tid];
#pragma unroll
        for (int t = 0; t < NT; t++) o += ds[t] * Wlin[t * NC + tid];
        out[tid] = o;
    }
}

// ---------------- host ----------------

extern "C" void kernel_launch(void* const* d_in, const int* in_sizes, int n_in,
                              void* d_out, int out_size, void* d_ws, size_t ws_size,
                              hipStream_t stream) {
    const float* x    = (const float*)d_in[0];
    const int*   ei   = (const int*)d_in[1];
    const int*   src  = ei;
    const int*   dst  = ei + NE;
    const float* W1   = (const float*)d_in[2];
    const float* b1   = (const float*)d_in[3];
    const float* W2   = (const float*)d_in[4];
    const float* b2   = (const float*)d_in[5];
    const float* tpl  = (const float*)d_in[6];
    const float* tplF = (const float*)d_in[7];
    const float* Wlin = (const float*)d_in[8];
    const float* blin = (const float*)d_in[9];
    float* out = (float*)d_out;

    char* w = (char*)d_ws;
    size_t off = 0;
    auto alloc = [&](size_t b) -> char* {
        off = (off + 255) & ~(size_t)255;
        char* p = w + off; off += b; return p;
    };
    float* bufA = (float*)alloc((size_t)NND * NH * 4);
    float* bufB = (float*)alloc((size_t)NND * NH * 4);
    float* bufH = (float*)alloc((size_t)NND * NF * 4);
    float* Mm   = (float*)alloc((size_t)NT * NMAT * 4);
    float* T    = (float*)alloc((size_t)NT * NMAT * 4);
    float* G    = (float*)alloc((size_t)NT * NMAT * 4);
    // --- zero group (one memset) ---
    int* cntD = (int*)alloc((size_t)NND * 4);
    int* cntS = (int*)alloc((size_t)NND * 4);
    int* cur1 = (int*)alloc((size_t)NND * 4);
    int* cur2 = (int*)alloc((size_t)NND * 4);
    double* dd = (double*)alloc((size_t)NT * 2 * 8);
    unsigned* scaleArr = (unsigned*)alloc((size_t)CG_ITERS * NT * 4);
    char* zend = w + off;
    // --- rest ---
    unsigned* bitmap = (unsigned*)alloc((size_t)781250 * 4);
    int* rpD  = (int*)alloc((size_t)(NND + 1) * 4);
    int* rpS  = (int*)alloc((size_t)(NND + 1) * 4);
    int* csrS = (int*)alloc((size_t)NE * 4);
    float* csrC = (float*)alloc((size_t)NE * 4);
    int* csrD2 = (int*)alloc((size_t)NE * 4);
    unsigned char* keep = (unsigned char*)alloc((size_t)NE);
    float* dinv  = (float*)alloc((size_t)NND * 4);
    float* c1row = (float*)alloc((size_t)NND * 4);
    float* sx    = (float*)alloc((size_t)NND * 4);
    float* sF    = (float*)alloc((size_t)100 * 4);
    float* c2row = (float*)alloc((size_t)100 * 4);

    hipMemsetAsync(cntD, 0, (size_t)(zend - (char*)cntD), stream);
    hipMemsetAsync(bitmap, 0, (size_t)781250 * 4, stream);

    // graph prep (merged passes)
    k_edge1<<<625, 256, 0, stream>>>(src, dst, cntD, bitmap, cntS, keep);
    k_exscan2<<<2, 1024, 0, stream>>>(cntD, rpD, dinv, cntS, rpS);
    k_scatter2<<<625, 256, 0, stream>>>(src, dst, keep, rpD, cur1, csrS, csrC, dinv,
                                        rpS, cur2, csrD2);

    // GCN
    k_gemm<<<dim3(NH / 64, (NND + 63) / 64), 256, 0, stream>>>(x, W1, bufA, NND, NH, NF);
    k_aggregate<<<NND, NH, 0, stream>>>(bufA, b1, bufB, rpD, csrS, csrC, dinv, 1);
    k_gemm<<<dim3(NF / 64, (NND + 63) / 64), 256, 0, stream>>>(bufB, W2, bufA, NND, NF, NH);
    k_aggregate<<<NND, NF, 0, stream>>>(bufA, b2, bufH, rpD, csrS, csrC, dinv, 0);

    // FGW prep
    k_prepnt<<<20, 256, 0, stream>>>(cntS, bufH, c1row, sx, tpl, tplF, c2row, sF);
    k_M<<<NND, 128, 0, stream>>>(bufH, tplF, sx, sF, Mm);
    k_Tinit<<<1954, 256, 0, stream>>>(T);

    // conditional gradient loop (scale slots pre-zeroed, one per CG iter)
    for (int t = 0; t < CG_ITERS; t++) {
        unsigned* sb = scaleArr + t * NT;
        k_grad<<<dim3(20, NT), 256, 0, stream>>>(T, Mm, c1row, c2row, tpl, rpS, csrD2, G, sb);
        float step = 2.f / (float)(t + 2);
        k_sinkhorn<<<NT, 512, 0, stream>>>(G, sb, T, step);
    }

    // final distances + linear head
    k_final<<<dim3(20, NT), 256, 0, stream>>>(T, Mm, c1row, c2row, tpl, rpS, csrD2, dd);
    k_out<<<1, 64, 0, stream>>>(dd, Wlin, blin, out);
}

// Round 5
// 688.558 us; speedup vs baseline: 2.8347x; 1.0198x over previous
//
#include <hip/hip_runtime.h>
#include <cstdint>

#define NND 5000
#define NE 160000
#define NF 128
#define NH 256
#define NT 10
#define MT 10
#define NC 8
#define NMAT (NND*MT)      // 50000 per template
#define CG_ITERS 5
#define SINK_IT 30

// ---------------- wave-level f32 sum (DPP, VALU pipe — no LDS) ----------------
// Result valid in lane 63. row_shr 1/2/4/8 then row_bcast15 (rows 1,3) and
// row_bcast31 (rows 2,3): classic GCN64 reduction (rocPRIM pattern).
#if __has_builtin(__builtin_amdgcn_update_dpp)
#define DPP_ADD(x, ctrl, rmask) \
    ((x) + __int_as_float(__builtin_amdgcn_update_dpp(0, __float_as_int(x), (ctrl), (rmask), 0xf, true)))
__device__ __forceinline__ float wave_sum63(float x) {
    x = DPP_ADD(x, 0x111, 0xf);   // row_shr:1
    x = DPP_ADD(x, 0x112, 0xf);   // row_shr:2
    x = DPP_ADD(x, 0x114, 0xf);   // row_shr:4
    x = DPP_ADD(x, 0x118, 0xf);   // row_shr:8
    x = DPP_ADD(x, 0x142, 0xa);   // row_bcast:15 -> rows 1,3
    x = DPP_ADD(x, 0x143, 0xc);   // row_bcast:31 -> rows 2,3
    return x;                      // lane 63 = full 64-lane sum
}
#else
__device__ __forceinline__ float wave_sum63(float x) {
#pragma unroll
    for (int off = 32; off; off >>= 1) x += __shfl_xor(x, off);
    return x;   // all lanes (incl. 63) hold the sum
}
#endif

__device__ __forceinline__ float frcp(float x) {
#if __has_builtin(__builtin_amdgcn_rcpf)
    return __builtin_amdgcn_rcpf(x);   // v_rcp_f32, ~1 ulp
#else
    return 1.f / x;
#endif
}

// ---------------- graph prep (merged) ----------------

// pass 1 over edges: dst-degree count + dedup bitmap + src-degree of distinct edges
__global__ void k_edge1(const int* __restrict__ src, const int* __restrict__ dst,
                        int* __restrict__ cntD, unsigned* __restrict__ bitmap,
                        int* __restrict__ cntS, unsigned char* __restrict__ keep) {
    for (int e = blockIdx.x*blockDim.x + threadIdx.x; e < NE; e += gridDim.x*blockDim.x) {
        int s = src[e], d = dst[e];
        atomicAdd(&cntD[d], 1);
        int key = s * NND + d;
        unsigned bit = 1u << (key & 31);
        unsigned old = atomicOr(&bitmap[key >> 5], bit);
        if (!(old & bit)) { keep[e] = 1; atomicAdd(&cntS[s], 1); }
        else keep[e] = 0;
    }
}

// block 0: cntD -> rpD (+ dinv); block 1: cntS -> rpS (+ c1row); block 2: c2row
__global__ void k_exscan2(const int* __restrict__ cntD, int* __restrict__ rpD,
                          float* __restrict__ dinv,
                          const int* __restrict__ cntS, int* __restrict__ rpS,
                          float* __restrict__ c1row,
                          const float* __restrict__ tpl, float* __restrict__ c2row) {
    const int T = 1024;
    int tid = threadIdx.x;
    if (blockIdx.x == 2) {
        if (tid < NT * MT) {
            int t = tid / MT, j = tid % MT;
            float s = 0.f;
            for (int k = 0; k < MT; k++) { float v = tpl[t * 100 + j * 10 + k]; s += v * v; }
            c2row[tid] = s * (1.f / MT);
        }
        return;
    }
    const int* cnt = blockIdx.x ? cntS : cntD;
    int* rp = blockIdx.x ? rpS : rpD;
    int C = (NND + T - 1) / T;
    int begin = tid * C, end = begin + C; if (end > NND) end = NND; if (begin > NND) begin = NND;
    int s = 0;
    for (int i = begin; i < end; i++) s += cnt[i];
    __shared__ int part[1024];
    part[tid] = s; __syncthreads();
    for (int off = 1; off < T; off <<= 1) {
        int v = (tid >= off) ? part[tid - off] : 0;
        __syncthreads();
        part[tid] += v;
        __syncthreads();
    }
    int run = part[tid] - s;   // exclusive
    for (int i = begin; i < end; i++) { rp[i] = run; run += cnt[i]; }
    if (tid == T - 1) rp[NND] = part[T - 1];
    if (blockIdx.x == 0)
        for (int i = begin; i < end; i++) dinv[i] = rsqrtf((float)(cnt[i] + 1));
    else
        for (int i = begin; i < end; i++) c1row[i] = (float)cnt[i] * (1.f / NND);
}

// pass 2 over edges: scatter into CSR-by-dst (weighted) and CSR-by-src (distinct)
__global__ void k_scatter2(const int* __restrict__ src, const int* __restrict__ dst,
                           const unsigned char* __restrict__ keep,
                           const int* __restrict__ rpD, int* __restrict__ cur1,
                           int* __restrict__ csrS, float* __restrict__ csrC,
                           const float* __restrict__ dinv,
                           const int* __restrict__ rpS, int* __restrict__ cur2,
                           int* __restrict__ csrD) {
    for (int e = blockIdx.x*blockDim.x + threadIdx.x; e < NE; e += gridDim.x*blockDim.x) {
        int s = src[e], d = dst[e];
        int pos = rpD[d] + atomicAdd(&cur1[d], 1);
        csrS[pos] = s;
        csrC[pos] = dinv[s] * dinv[d];
        if (keep[e]) {
            int p2 = rpS[s] + atomicAdd(&cur2[s], 1);
            csrD[p2] = d;
        }
    }
}

// ---------------- GCN ----------------
// GCN layer = agg(x @ W) + b; aggregation is linear in features, so we use
// (agg x) @ W + b for layer 1 (aggregate 128-dim instead of 256-dim rows).

__global__ __launch_bounds__(256) void k_gemm(const float* __restrict__ A,
                                              const float* __restrict__ B,
                                              float* __restrict__ C, int M, int N, int K,
                                              const float* __restrict__ bias, int relu) {
    const int BM = 64, BN = 64, BK = 16;
    __shared__ float As[BK][BM + 1];
    __shared__ float Bs[BK][BN];
    int tid = threadIdx.x;
    int row0 = blockIdx.y * BM, col0 = blockIdx.x * BN;
    int tx = tid % 16, ty = tid / 16;
    float acc[4][4] = {};
    for (int k0 = 0; k0 < K; k0 += BK) {
#pragma unroll
        for (int l = 0; l < 4; l++) {
            int idx = tid + l * 256;
            int r = idx / BK, kk = idx % BK;
            int gr = row0 + r;
            As[kk][r] = (gr < M) ? A[(size_t)gr * K + k0 + kk] : 0.f;
        }
#pragma unroll
        for (int l = 0; l < 4; l++) {
            int idx = tid + l * 256;
            int kk = idx / BN, c = idx % BN;
            Bs[kk][c] = B[(size_t)(k0 + kk) * N + col0 + c];
        }
        __syncthreads();
#pragma unroll
        for (int kk = 0; kk < BK; kk++) {
            float a[4], b[4];
#pragma unroll
            for (int i = 0; i < 4; i++) a[i] = As[kk][ty * 4 + i];
#pragma unroll
            for (int j = 0; j < 4; j++) b[j] = Bs[kk][tx * 4 + j];
#pragma unroll
            for (int i = 0; i < 4; i++)
#pragma unroll
                for (int j = 0; j < 4; j++) acc[i][j] += a[i] * b[j];
        }
        __syncthreads();
    }
#pragma unroll
    for (int i = 0; i < 4; i++) {
        int gr = row0 + ty * 4 + i;
        if (gr < M) {
#pragma unroll
            for (int j = 0; j < 4; j++) {
                int gc = col0 + tx * 4 + j;
                float o = acc[i][j];
                if (bias) o += bias[gc];
                if (relu) o = fmaxf(o, 0.f);
                C[(size_t)gr * N + gc] = o;
            }
        }
    }
}

// aggregation over 128-dim rows (bias optional)
__global__ __launch_bounds__(128) void k_aggregate(const float* __restrict__ hin,
                            const float* __restrict__ bias,
                            float* __restrict__ hout, const int* __restrict__ rp,
                            const int* __restrict__ csrS, const float* __restrict__ csrC,
                            const float* __restrict__ dinv) {
    int v = blockIdx.x;
    int f = threadIdx.x;
    float dv = dinv[v];
    float acc = hin[(size_t)v * NF + f] * dv * dv;   // structural self-loop
    int e0 = rp[v], e1 = rp[v + 1];
    for (int e = e0; e < e1; e++)
        acc += hin[(size_t)csrS[e] * NF + f] * csrC[e];
    if (bias) acc += bias[f];
    hout[(size_t)v * NF + f] = acc;
}

// ---------------- FGW prep ----------------

// feature cost M (computes sx and sF inline; no prep kernel needed)
__global__ __launch_bounds__(128) void k_M(const float* __restrict__ h,
                    const float* __restrict__ tplF,
                    float* __restrict__ Mout) {
    int i = blockIdx.x;
    int tid = threadIdx.x;
    int lane = tid & 63, w = tid >> 6;
    __shared__ float hrow[NF];
    __shared__ float part[2];
    float hv = h[(size_t)i * NF + tid];
    hrow[tid] = hv;
    float ps = wave_sum63(hv * hv);
    if (lane == 63) part[w] = ps;
    __syncthreads();
    float sx = part[0] + part[1];
    int c = tid;
    if (c < NT * MT) {
        const float* Fc = tplF + (size_t)c * NF;
        float dot = 0.f, nrm = 0.f;
        for (int f = 0; f < NF; f++) {
            float fv = Fc[f];
            dot = fmaf(hrow[f], fv, dot);
            nrm = fmaf(fv, fv, nrm);
        }
        int t = c / MT, j = c % MT;
        Mout[(size_t)t * NMAT + (size_t)i * MT + j] = sx + nrm - 2.f * dot;
    }
}

__global__ void k_Tinit(float* __restrict__ T) {
    for (int idx = blockIdx.x*blockDim.x + threadIdx.x; idx < NT * NMAT; idx += gridDim.x*blockDim.x)
        T[idx] = 1.f / (float)NMAT;
}

// ---------------- CG iteration ----------------

__global__ __launch_bounds__(256) void k_grad(const float* __restrict__ T, const float* __restrict__ Mm,
                                              const float* __restrict__ c1row, const float* __restrict__ c2row,
                                              const float* __restrict__ tpl,
                                              const int* __restrict__ rpS, const int* __restrict__ csrD,
                                              float* __restrict__ G, unsigned* __restrict__ scaleBits) {
    int t = blockIdx.y;
    int tid = threadIdx.x;
    __shared__ float tC2[100];
    if (tid < 100) tC2[tid] = 2.f * tpl[t * 100 + tid];
    __syncthreads();
    int i = blockIdx.x * 256 + tid;
    float amax = 0.f;
    if (i < NND) {
        const float* Tt = T + (size_t)t * NMAT;
        const float* Mt = Mm + (size_t)t * NMAT;
        float* Gt = G + (size_t)t * NMAT;
        float L[MT];
#pragma unroll
        for (int j = 0; j < MT; j++) L[j] = 0.f;
        int e0 = rpS[i], e1 = rpS[i + 1];
        for (int e = e0; e < e1; e++) {
            int k = csrD[e];
            const float* Tk = Tt + (size_t)k * MT;
#pragma unroll
            for (int j = 0; j < MT; j++) L[j] += Tk[j];
        }
        float c1 = c1row[i];
#pragma unroll
        for (int j = 0; j < MT; j++) {
            float s = 0.f;
#pragma unroll
            for (int k = 0; k < MT; k++) s += L[k] * tC2[j * 10 + k];
            // grad = (1-a)M + 2a*(constC - C1 T (2C2)^T), a=0.5
            float g = 0.5f * Mt[(size_t)i * MT + j] + (c1 + c2row[t * 10 + j] - s);
            Gt[(size_t)i * MT + j] = g;
            amax = fmaxf(amax, fabsf(g));
        }
    }
    __shared__ float red[256];
    red[tid] = amax; __syncthreads();
    for (int off = 128; off > 0; off >>= 1) {
        if (tid < off) red[tid] = fmaxf(red[tid], red[tid + off]);
        __syncthreads();
    }
    if (tid == 0) atomicMax(&scaleBits[t], __float_as_uint(red[0]));
}

// one block per template; all-f32 scaling-form sinkhorn.
// Range safety: |G*inv| <= 50 exactly (scale = max|G|), so K in [1.9e-22, 5.2e21]
// and all intermediates stay inside f32 (first-iter colsum <= 2.6e25).
// waves_per_eu(1,2): cap occupancy so Kf[10][10] stays in VGPRs (256-reg budget);
// round-4 default targeted 8 waves/EU (64 VGPR) and spilled K to scratch.
// Column reduce via DPP wave sums (VALU pipe) — no LDS tree, no bank conflicts.
__global__ __launch_bounds__(512)
__attribute__((amdgpu_waves_per_eu(1, 2)))
void k_sinkhorn(const float* __restrict__ G,
                const unsigned* __restrict__ scaleBits,
                float* __restrict__ T, float step) {
    int t = blockIdx.x;
    int tid = threadIdx.x;
    int lane = tid & 63, w = tid >> 6;
    float sc = __uint_as_float(scaleBits[t]) + 1e-9f;
    float inv = -1.f / (0.02f * sc);
    const float* Gt = G + (size_t)t * NMAT;
    float* Tt = T + (size_t)t * NMAT;

    __shared__ float wred[8][10];
    __shared__ float vbc[12];

    float Kf[10][10];
    float u[10];
#pragma unroll
    for (int r = 0; r < 10; r++) {
        int i = tid + r * 512;
        if (i < NND) {
            u[r] = 1.f;
            const float2* Gr = (const float2*)(Gt + (size_t)i * 10);
#pragma unroll
            for (int h = 0; h < 5; h++) {
                float2 g = Gr[h];
                Kf[r][2*h]   = __expf(g.x * inv);
                Kf[r][2*h+1] = __expf(g.y * inv);
            }
        } else {
            u[r] = 0.f;
#pragma unroll
            for (int j = 0; j < 10; j++) Kf[r][j] = 0.f;
        }
    }

    float vv[10];

    for (int it = 0; it < SINK_IT; it++) {
        // per-thread column partials over this thread's 10 rows
        float S[10];
#pragma unroll
        for (int j = 0; j < 10; j++) S[j] = 0.f;
#pragma unroll
        for (int r = 0; r < 10; r++) {
            float ur = u[r];
#pragma unroll
            for (int j = 0; j < 10; j++) S[j] = fmaf(Kf[r][j], ur, S[j]);
        }
        // DPP wave reduction (result in lane 63), lane 63 publishes
#pragma unroll
        for (int j = 0; j < 10; j++) {
            float s = wave_sum63(S[j]);
            if (lane == 63) wred[w][j] = s;
        }
        __syncthreads();
        // 10 threads combine the 8 wave partials, publish v = q / colsum
        if (tid < 10) {
            float s = 0.f;
#pragma unroll
            for (int q = 0; q < 8; q++) s += wred[q][tid];
            vbc[tid] = 0.1f * frcp(fmaxf(s, 1e-30f));
        }
        __syncthreads();
#pragma unroll
        for (int j = 0; j < 10; j++) vv[j] = vbc[j];      // LDS broadcast reads
        // row update: u = p / (K v)
#pragma unroll
        for (int r = 0; r < 10; r++) {
            float R = 0.f;
#pragma unroll
            for (int j = 0; j < 10; j++) R = fmaf(Kf[r][j], vv[j], R);
            u[r] = (tid + r * 512 < NND) ? (2e-4f * frcp(fmaxf(R, 1e-30f))) : 0.f;
        }
    }

    // T += step * (u K v - T)
#pragma unroll
    for (int r = 0; r < 10; r++) {
        int i = tid + r * 512;
        if (i < NND) {
            float ur = u[r];
            float2* Tr = (float2*)(Tt + (size_t)i * 10);
#pragma unroll
            for (int h = 0; h < 5; h++) {
                float2 v = Tr[h];
                v.x += step * (ur * Kf[r][2*h]   * vv[2*h]   - v.x);
                v.y += step * (ur * Kf[r][2*h+1] * vv[2*h+1] - v.y);
                Tr[h] = v;
            }
        }
    }
}

// ---------------- final distance + head ----------------

__global__ __launch_bounds__(256) void k_final(const float* __restrict__ T, const float* __restrict__ Mm,
                                               const float* __restrict__ c1row, const float* __restrict__ c2row,
                                               const float* __restrict__ tpl,
                                               const int* __restrict__ rpS, const int* __restrict__ csrD,
                                               double* __restrict__ dd) {
    int t = blockIdx.y;
    int tid = threadIdx.x;
    __shared__ float tC2[100];
    if (tid < 100) tC2[tid] = 2.f * tpl[t * 100 + tid];
    __syncthreads();
    int i = blockIdx.x * 256 + tid;
    double msum = 0.0, tsum = 0.0;
    if (i < NND) {
        const float* Tt = T + (size_t)t * NMAT;
        const float* Mt = Mm + (size_t)t * NMAT;
        float L[MT];
#pragma unroll
        for (int j = 0; j < MT; j++) L[j] = 0.f;
        int e0 = rpS[i], e1 = rpS[i + 1];
        for (int e = e0; e < e1; e++) {
            int k = csrD[e];
            const float* Tk = Tt + (size_t)k * MT;
#pragma unroll
            for (int j = 0; j < MT; j++) L[j] += Tk[j];
        }
        float c1 = c1row[i];
#pragma unroll
        for (int j = 0; j < MT; j++) {
            float s = 0.f;
#pragma unroll
            for (int k = 0; k < MT; k++) s += L[k] * tC2[j * 10 + k];
            float ts = c1 + c2row[t * 10 + j] - s;
            float Tv = Tt[(size_t)i * MT + j];
            msum += (double)(Mt[(size_t)i * MT + j] * Tv);
            tsum += (double)(ts * Tv);
        }
    }
    __shared__ double r1[256], r2[256];
    r1[tid] = msum; r2[tid] = tsum; __syncthreads();
    for (int off = 128; off > 0; off >>= 1) {
        if (tid < off) { r1[tid] += r1[tid + off]; r2[tid] += r2[tid + off]; }
        __syncthreads();
    }
    if (tid == 0) { atomicAdd(&dd[t * 2], r1[0]); atomicAdd(&dd[t * 2 + 1], r2[0]); }
}

__global__ void k_out(const double* __restrict__ dd, const float* __restrict__ Wlin,
                      const float* __restrict__ blin, float* __restrict__ out) {
    int tid = threadIdx.x;
    __shared__ float ds[NT];
    if (tid < NT) ds[tid] = 0.5f * (float)(dd[2 * tid] + dd[2 * tid + 1]);
    __syncthreads();
    if (tid < NC) {
        float o = blin[tid];
#pragma unroll
        for (int t = 0; t < NT; t++) o += ds[t] * Wlin[t * NC + tid];
        out[tid] = o;
    }
}

// ---------------- host ----------------

extern "C" void kernel_launch(void* const* d_in, const int* in_sizes, int n_in,
                              void* d_out, int out_size, void* d_ws, size_t ws_size,
                              hipStream_t stream) {
    const float* x    = (const float*)d_in[0];
    const int*   ei   = (const int*)d_in[1];
    const int*   src  = ei;
    const int*   dst  = ei + NE;
    const float* W1   = (const float*)d_in[2];
    const float* b1   = (const float*)d_in[3];
    const float* W2   = (const float*)d_in[4];
    const float* b2   = (const float*)d_in[5];
    const float* tpl  = (const float*)d_in[6];
    const float* tplF = (const float*)d_in[7];
    const float* Wlin = (const float*)d_in[8];
    const float* blin = (const float*)d_in[9];
    float* out = (float*)d_out;

    char* w = (char*)d_ws;
    size_t off = 0;
    auto alloc = [&](size_t b) -> char* {
        off = (off + 255) & ~(size_t)255;
        char* p = w + off; off += b; return p;
    };
    float* bufA = (float*)alloc((size_t)NND * NH * 4);   // aggX / t2 (reused)
    float* bufB = (float*)alloc((size_t)NND * NH * 4);   // h1
    float* bufH = (float*)alloc((size_t)NND * NF * 4);   // h2
    float* Mm   = (float*)alloc((size_t)NT * NMAT * 4);
    float* T    = (float*)alloc((size_t)NT * NMAT * 4);
    float* G    = (float*)alloc((size_t)NT * NMAT * 4);
    // --- zero group (one memset) ---
    int* cntD = (int*)alloc((size_t)NND * 4);
    int* cntS = (int*)alloc((size_t)NND * 4);
    int* cur1 = (int*)alloc((size_t)NND * 4);
    int* cur2 = (int*)alloc((size_t)NND * 4);
    double* dd = (double*)alloc((size_t)NT * 2 * 8);
    unsigned* scaleArr = (unsigned*)alloc((size_t)CG_ITERS * NT * 4);
    char* zend = w + off;
    // --- rest ---
    unsigned* bitmap = (unsigned*)alloc((size_t)781250 * 4);
    int* rpD  = (int*)alloc((size_t)(NND + 1) * 4);
    int* rpS  = (int*)alloc((size_t)(NND + 1) * 4);
    int* csrS = (int*)alloc((size_t)NE * 4);
    float* csrC = (float*)alloc((size_t)NE * 4);
    int* csrD2 = (int*)alloc((size_t)NE * 4);
    unsigned char* keep = (unsigned char*)alloc((size_t)NE);
    float* dinv  = (float*)alloc((size_t)NND * 4);
    float* c1row = (float*)alloc((size_t)NND * 4);
    float* c2row = (float*)alloc((size_t)100 * 4);

    hipMemsetAsync(cntD, 0, (size_t)(zend - (char*)cntD), stream);
    hipMemsetAsync(bitmap, 0, (size_t)781250 * 4, stream);

    // graph prep (merged passes)
    k_edge1<<<625, 256, 0, stream>>>(src, dst, cntD, bitmap, cntS, keep);
    k_exscan2<<<3, 1024, 0, stream>>>(cntD, rpD, dinv, cntS, rpS, c1row, tpl, c2row);
    k_scatter2<<<625, 256, 0, stream>>>(src, dst, keep, rpD, cur1, csrS, csrC, dinv,
                                        rpS, cur2, csrD2);

    // GCN: layer1 = relu((agg x) @ W1 + b1); layer2 = agg(h1 @ W2) + b2
    k_aggregate<<<NND, NF, 0, stream>>>(x, nullptr, bufA, rpD, csrS, csrC, dinv);
    k_gemm<<<dim3(NH / 64, (NND + 63) / 64), 256, 0, stream>>>(bufA, W1, bufB, NND, NH, NF, b1, 1);
    k_gemm<<<dim3(NF / 64, (NND + 63) / 64), 256, 0, stream>>>(bufB, W2, bufA, NND, NF, NH, nullptr, 0);
    k_aggregate<<<NND, NF, 0, stream>>>(bufA, b2, bufH, rpD, csrS, csrC, dinv);

    // FGW prep
    k_M<<<NND, 128, 0, stream>>>(bufH, tplF, Mm);
    k_Tinit<<<1954, 256, 0, stream>>>(T);

    // conditional gradient loop (scale slots pre-zeroed, one per CG iter)
    for (int t = 0; t < CG_ITERS; t++) {
        unsigned* sb = scaleArr + t * NT;
        k_grad<<<dim3(20, NT), 256, 0, stream>>>(T, Mm, c1row, c2row, tpl, rpS, csrD2, G, sb);
        float step = 2.f / (float)(t + 2);
        k_sinkhorn<<<NT, 512, 0, stream>>>(G, sb, T, step);
    }

    // final distances + linear head
    k_final<<<dim3(20, NT), 256, 0, stream>>>(T, Mm, c1row, c2row, tpl, rpS, csrD2, dd);
    k_out<<<1, 64, 0, stream>>>(dd, Wlin, blin, out);
}